// Round 4
// baseline (41.364 us; speedup 1.0000x reference)
//
#include <hip/hip_runtime.h>

#define BB 16
#define SS 16
#define LL 128
#define DD 768
#define AA 8
#define TT 8
#define PAD_ID 1
#define NARG 24          // 3 arg types * 8 args
#define NROW 25          // 1 mean row + 24 arg rows
#define WSTRIDE 32       // padded row length for float4 reads

__global__ __launch_bounds__(256) void srl_kernel(
    const int* __restrict__ sid_g,
    const int* __restrict__ mask_g,
    const float* __restrict__ emb_g,
    const int* __restrict__ pred_g,
    const int* __restrict__ a0_g,
    const int* __restrict__ a1_g,
    float* __restrict__ out)
{
    __shared__ int   sid[LL];
    __shared__ float maskf[LL];
    __shared__ float W[LL][WSTRIDE];
    __shared__ float coeff[NARG][TT];
    __shared__ float validf[NARG][TT];
    __shared__ int   toks[NARG][TT];
    __shared__ float inv_msum;

    const int bs  = blockIdx.x;
    const int tid = threadIdx.x;

    // ---- Phase A: stage sentence ids + mask ----
    if (tid < LL) {
        sid[tid]   = sid_g[bs * LL + tid];
        maskf[tid] = (float)mask_g[bs * LL + tid];
    }
    __syncthreads();

    // ---- Phase B1: per-token match count + valid (threads 0..191),
    //      mask-sum reduction on wave 3 (threads 192..255) ----
    if (tid < NARG * TT) {
        const int j = tid >> 3;         // arg index 0..23
        const int t = tid & 7;          // token index
        const int k = j >> 3;           // arg type 0..2
        const int a = j & 7;            // arg slot
        const int* src = (k == 0) ? pred_g : (k == 1) ? a0_g : a1_g;
        const int tok = src[bs * AA * TT + a * TT + t];
        int cnt = 0;
        for (int l = 0; l < LL; ++l) cnt += (sid[l] == tok) ? 1 : 0;
        const float v = (tok != PAD_ID) ? 1.0f : 0.0f;
        toks[j][t]   = tok;
        validf[j][t] = v;
        coeff[j][t]  = v / (float)(cnt > 1 ? cnt : 1);
    } else {
        const int lane = tid - 192;     // lanes of wave 3
        float s = maskf[lane] + maskf[lane + 64];
        for (int off = 32; off; off >>= 1) s += __shfl_xor(s, off, 64);
        if (lane == 0) inv_msum = 1.0f / fmaxf(s, 1.0f);
    }
    __syncthreads();

    // ---- Phase B2: fold 1/n_valid into coefficients ----
    if (tid < NARG) {
        float nv = 0.0f;
        #pragma unroll
        for (int t = 0; t < TT; ++t) nv += validf[tid][t];
        const float inv = 1.0f / fmaxf(nv, 1.0f);
        #pragma unroll
        for (int t = 0; t < TT; ++t) coeff[tid][t] *= inv;
    }
    __syncthreads();

    // ---- Phase C: materialize W[l][r] (rows 25..31 zero padding) ----
    for (int idx = tid; idx < LL * WSTRIDE; idx += 256) {
        const int l = idx >> 5;
        const int r = idx & 31;
        float w = 0.0f;
        if (r == 0) {
            w = maskf[l] * inv_msum;
        } else if (r <= NARG) {
            const int j  = r - 1;
            const int sl = sid[l];
            #pragma unroll
            for (int t = 0; t < TT; ++t)
                w += (sl == toks[j][t]) ? coeff[j][t] : 0.0f;
        }
        W[l][r] = w;
    }
    __syncthreads();

    // ---- Phase D: weighted reduction over L, one column per thread ----
    const int col = blockIdx.y * 256 + tid;
    const float* ep = emb_g + (size_t)bs * (LL * DD) + col;

    float acc[NROW];
    #pragma unroll
    for (int r = 0; r < NROW; ++r) acc[r] = 0.0f;

    #pragma unroll 4
    for (int l = 0; l < LL; ++l) {
        const float e = ep[(size_t)l * DD];
        const float4* wr = reinterpret_cast<const float4*>(&W[l][0]);
        const float4 w0 = wr[0];
        const float4 w1 = wr[1];
        const float4 w2 = wr[2];
        const float4 w3 = wr[3];
        const float4 w4 = wr[4];
        const float4 w5 = wr[5];
        const float4 w6 = wr[6];
        acc[0]  += w0.x * e;  acc[1]  += w0.y * e;  acc[2]  += w0.z * e;  acc[3]  += w0.w * e;
        acc[4]  += w1.x * e;  acc[5]  += w1.y * e;  acc[6]  += w1.z * e;  acc[7]  += w1.w * e;
        acc[8]  += w2.x * e;  acc[9]  += w2.y * e;  acc[10] += w2.z * e;  acc[11] += w2.w * e;
        acc[12] += w3.x * e;  acc[13] += w3.y * e;  acc[14] += w3.z * e;  acc[15] += w3.w * e;
        acc[16] += w4.x * e;  acc[17] += w4.y * e;  acc[18] += w4.z * e;  acc[19] += w4.w * e;
        acc[20] += w5.x * e;  acc[21] += w5.y * e;  acc[22] += w5.z * e;  acc[23] += w5.w * e;
        acc[24] += w6.x * e;
    }

    // ---- Epilogue: coalesced stores ----
    float* out0 = out;                               // [B*S, D]
    float* outA = out + (size_t)BB * SS * DD;        // 3 x [B*S, A, D]
    out0[(size_t)bs * DD + col] = acc[0];
    #pragma unroll
    for (int k = 0; k < 3; ++k) {
        #pragma unroll
        for (int a = 0; a < AA; ++a) {
            outA[(size_t)k * (BB * SS * AA * DD) + ((size_t)bs * AA + a) * DD + col]
                = acc[1 + k * 8 + a];
        }
    }
}

extern "C" void kernel_launch(void* const* d_in, const int* in_sizes, int n_in,
                              void* d_out, int out_size, void* d_ws, size_t ws_size,
                              hipStream_t stream) {
    const int*   sid  = (const int*)d_in[0];
    const int*   mask = (const int*)d_in[1];
    const float* emb  = (const float*)d_in[2];
    const int*   pred = (const int*)d_in[3];
    const int*   a0   = (const int*)d_in[4];
    const int*   a1   = (const int*)d_in[5];
    float* outp = (float*)d_out;

    dim3 grid(BB * SS, DD / 256);
    srl_kernel<<<grid, dim3(256), 0, stream>>>(sid, mask, emb, pred, a0, a1, outp);
}